// Round 12
// baseline (153.980 us; speedup 1.0000x reference)
//
#include <hip/hip_runtime.h>
#include <math.h>

#define N_NODES 10000
#define N_EDGES 320000
#define F_IN 512
#define HID 256
#define PAD_DEG 80    // max in-degree ~60 (Poisson(32) over 10k nodes); 80 is +8.5 sigma
#define LDSTR 40      // LDS row stride in halves (32 + 8 pad, keeps 16B alignment)
#define N_TILES (157 * 4)     // 157 row-tiles x 4 col-tiles of 64x64
#define BUILD_BLKS ((N_EDGES + 255) / 256)   // 1250

typedef _Float16 half8 __attribute__((ext_vector_type(8)));
typedef float floatx4 __attribute__((ext_vector_type(4)));

__device__ __forceinline__ void fma4(float4& acc, float s, const float4& v) {
    acc.x += s * v.x; acc.y += s * v.y; acc.z += s * v.z; acc.w += s * v.w;
}

// ---- k_pre: zero degree counters + W1 [512][256] -> transposed fp16 hi/lo split ----

__global__ __launch_bounds__(256) void k_pre(const float* __restrict__ W1,
                                             int* __restrict__ count,
                                             _Float16* __restrict__ Bt_hi,
                                             _Float16* __restrict__ Bt_lo) {
    int i = blockIdx.x * blockDim.x + threadIdx.x;
    if (i < 10240) count[i] = 0;
    int k = i >> 8, n = i & 255;
    float v = W1[i];
    _Float16 hi = (_Float16)v;
    Bt_hi[n * F_IN + k] = hi;
    Bt_lo[n * F_IN + k] = (_Float16)(v - (float)hi);
}

// ---- k_combo: GEMM tiles (blocks 0..627) || CSR build (blocks 628..1877) ----

__global__ __launch_bounds__(256) void k_combo(const float* __restrict__ A,
                                               const _Float16* __restrict__ Bt_hi,
                                               const _Float16* __restrict__ Bt_lo,
                                               const float* __restrict__ b1,
                                               float* __restrict__ h0,
                                               const int* __restrict__ ei,
                                               int* __restrict__ count,
                                               int* __restrict__ csr) {
    __shared__ _Float16 As_hi[64 * LDSTR], As_lo[64 * LDSTR];
    __shared__ _Float16 Bs_hi[64 * LDSTR], Bs_lo[64 * LDSTR];
    const int tid = threadIdx.x;

    if (blockIdx.x >= N_TILES) {
        // ---------- CSR build half ----------
        int e = (blockIdx.x - N_TILES) * 256 + tid;
        if (e < N_EDGES) {
            int src = ei[e];
            int dst = ei[N_EDGES + e];
            int pos = atomicAdd(&count[dst], 1);   // final value = in-degree
            csr[dst * PAD_DEG + pos] = src;
        }
        return;
    }

    // ---------- GEMM half: h0 = feature @ W1 + b1, 3-term fp16-split MFMA ----------
    const int lane = tid & 63, w = tid >> 6;
    const int wm = (w >> 1) * 32, wn = (w & 1) * 32;
    const int quad = lane >> 4, l15 = lane & 15;
    const int r = tid >> 2, c = (tid & 3) << 3;      // stage 64 rows x 32 halves
    const int t = blockIdx.x;
    const int row0 = (t >> 2) * 64, col0 = (t & 3) * 64;
    floatx4 acc[2][2] = {};

    for (int k0 = 0; k0 < F_IN; k0 += 32) {
        float av[8];
        int arow = row0 + r;
        if (arow < N_NODES) {
            float4 v0 = *(const float4*)(A + (size_t)arow * F_IN + k0 + c);
            float4 v1 = *(const float4*)(A + (size_t)arow * F_IN + k0 + c + 4);
            av[0] = v0.x; av[1] = v0.y; av[2] = v0.z; av[3] = v0.w;
            av[4] = v1.x; av[5] = v1.y; av[6] = v1.z; av[7] = v1.w;
        } else {
            #pragma unroll
            for (int i = 0; i < 8; ++i) av[i] = 0.f;
        }
        half8 hhi, hlo;
        #pragma unroll
        for (int i = 0; i < 8; ++i) {
            _Float16 h = (_Float16)av[i];
            hhi[i] = h;
            hlo[i] = (_Float16)(av[i] - (float)h);
        }
        *(half8*)&As_hi[r * LDSTR + c] = hhi;
        *(half8*)&As_lo[r * LDSTR + c] = hlo;
        *(half8*)&Bs_hi[r * LDSTR + c] = *(const half8*)(Bt_hi + (size_t)(col0 + r) * F_IN + k0 + c);
        *(half8*)&Bs_lo[r * LDSTR + c] = *(const half8*)(Bt_lo + (size_t)(col0 + r) * F_IN + k0 + c);
        __syncthreads();
        half8 a_hi[2], a_lo[2], b_hi[2], b_lo[2];
        #pragma unroll
        for (int mi = 0; mi < 2; ++mi) {
            int mr = wm + mi * 16 + l15;             // A[m=lane&15][k=quad*8+j]
            a_hi[mi] = *(half8*)&As_hi[mr * LDSTR + quad * 8];
            a_lo[mi] = *(half8*)&As_lo[mr * LDSTR + quad * 8];
        }
        #pragma unroll
        for (int ni = 0; ni < 2; ++ni) {
            int nr = wn + ni * 16 + l15;             // B[k][n] from transposed tile
            b_hi[ni] = *(half8*)&Bs_hi[nr * LDSTR + quad * 8];
            b_lo[ni] = *(half8*)&Bs_lo[nr * LDSTR + quad * 8];
        }
        #pragma unroll
        for (int mi = 0; mi < 2; ++mi)
            #pragma unroll
            for (int ni = 0; ni < 2; ++ni) {
                acc[mi][ni] = __builtin_amdgcn_mfma_f32_16x16x32_f16(a_hi[mi], b_hi[ni], acc[mi][ni], 0, 0, 0);
                acc[mi][ni] = __builtin_amdgcn_mfma_f32_16x16x32_f16(a_hi[mi], b_lo[ni], acc[mi][ni], 0, 0, 0);
                acc[mi][ni] = __builtin_amdgcn_mfma_f32_16x16x32_f16(a_lo[mi], b_hi[ni], acc[mi][ni], 0, 0, 0);
            }
        __syncthreads();
    }
    // epilogue: C/D layout col=lane&15, row=quad*4+reg
    #pragma unroll
    for (int mi = 0; mi < 2; ++mi)
        #pragma unroll
        for (int ni = 0; ni < 2; ++ni) {
            int colb = col0 + wn + ni * 16 + l15;
            float bias = b1[colb];
            #pragma unroll
            for (int reg = 0; reg < 4; ++reg) {
                int rowb = row0 + wm + mi * 16 + quad * 4 + reg;
                if (rowb < N_NODES) h0[(size_t)rowb * HID + colb] = acc[mi][ni][reg] + bias;
            }
        }
}

// ---- k_agg1: u0 = relu(agg(h0)) @ W2 + b2 ----
// one wave/node, float4 (16B/lane), UNROLL 16 -> 16 independent gathers in flight

__global__ __launch_bounds__(256) void k_agg1(const float* __restrict__ h0,
                                              const int* __restrict__ csr,
                                              const int* __restrict__ count,
                                              const float* __restrict__ W2,
                                              const float* __restrict__ b2,
                                              float* __restrict__ u0) {
    int n = blockIdx.x * 4 + (threadIdx.x >> 6);
    int lane = threadIdx.x & 63;
    if (n >= N_NODES) return;
    int deg = count[n];
    float degd = (float)(deg > 0 ? deg : 1);
    const int* row = csr + (size_t)n * PAD_DEG;
    int off = lane << 2;
    float4 acc0 = {0,0,0,0}, acc1 = {0,0,0,0}, acc2 = {0,0,0,0}, acc3 = {0,0,0,0};
    int j = 0;
    for (; j + 16 <= deg; j += 16) {
        int   s[16];
        int   cw[16];
        float4 v[16];
        #pragma unroll
        for (int q = 0; q < 16; ++q) s[q] = row[j + q];      // wave-uniform broadcast
        #pragma unroll
        for (int q = 0; q < 16; ++q) cw[q] = count[s[q]];    // 16 tiny gathers in flight
        #pragma unroll
        for (int q = 0; q < 16; ++q)
            v[q] = *(const float4*)(h0 + (size_t)s[q] * HID + off);  // 16 16B gathers
        #pragma unroll
        for (int q = 0; q < 16; ++q) {
            float wq = rsqrtf((float)(cw[q] > 0 ? cw[q] : 1) * degd);
            if ((q & 3) == 0) fma4(acc0, wq, v[q]);
            else if ((q & 3) == 1) fma4(acc1, wq, v[q]);
            else if ((q & 3) == 2) fma4(acc2, wq, v[q]);
            else fma4(acc3, wq, v[q]);
        }
    }
    for (; j + 8 <= deg; j += 8) {
        int s0 = row[j+0], s1 = row[j+1], s2 = row[j+2], s3 = row[j+3];
        int s4 = row[j+4], s5 = row[j+5], s6 = row[j+6], s7 = row[j+7];
        int c0 = count[s0], c1 = count[s1], c2 = count[s2], c3 = count[s3];
        int c4 = count[s4], c5 = count[s5], c6 = count[s6], c7 = count[s7];
        float4 v0 = *(const float4*)(h0 + (size_t)s0 * HID + off);
        float4 v1 = *(const float4*)(h0 + (size_t)s1 * HID + off);
        float4 v2 = *(const float4*)(h0 + (size_t)s2 * HID + off);
        float4 v3 = *(const float4*)(h0 + (size_t)s3 * HID + off);
        float4 v4 = *(const float4*)(h0 + (size_t)s4 * HID + off);
        float4 v5 = *(const float4*)(h0 + (size_t)s5 * HID + off);
        float4 v6 = *(const float4*)(h0 + (size_t)s6 * HID + off);
        float4 v7 = *(const float4*)(h0 + (size_t)s7 * HID + off);
        fma4(acc0, rsqrtf((float)(c0 > 0 ? c0 : 1) * degd), v0);
        fma4(acc1, rsqrtf((float)(c1 > 0 ? c1 : 1) * degd), v1);
        fma4(acc2, rsqrtf((float)(c2 > 0 ? c2 : 1) * degd), v2);
        fma4(acc3, rsqrtf((float)(c3 > 0 ? c3 : 1) * degd), v3);
        fma4(acc0, rsqrtf((float)(c4 > 0 ? c4 : 1) * degd), v4);
        fma4(acc1, rsqrtf((float)(c5 > 0 ? c5 : 1) * degd), v5);
        fma4(acc2, rsqrtf((float)(c6 > 0 ? c6 : 1) * degd), v6);
        fma4(acc3, rsqrtf((float)(c7 > 0 ? c7 : 1) * degd), v7);
    }
    for (; j < deg; ++j) {
        int s = row[j];
        int cs = count[s];
        float4 v = *(const float4*)(h0 + (size_t)s * HID + off);
        fma4(acc0, rsqrtf((float)(cs > 0 ? cs : 1) * degd), v);
    }
    acc0.x += acc1.x + acc2.x + acc3.x;
    acc0.y += acc1.y + acc2.y + acc3.y;
    acc0.z += acc1.z + acc2.z + acc3.z;
    acc0.w += acc1.w + acc2.w + acc3.w;
    acc0.x = fmaxf(acc0.x, 0.f); acc0.y = fmaxf(acc0.y, 0.f);
    acc0.z = fmaxf(acc0.z, 0.f); acc0.w = fmaxf(acc0.w, 0.f);
    float4 wa = *(const float4*)(W2 + (lane << 3));
    float4 wb = *(const float4*)(W2 + (lane << 3) + 4);
    float p0 = acc0.x * wa.x + acc0.y * wa.z + acc0.z * wb.x + acc0.w * wb.z;
    float p1 = acc0.x * wa.y + acc0.y * wa.w + acc0.z * wb.y + acc0.w * wb.w;
    #pragma unroll
    for (int o = 32; o > 0; o >>= 1) {
        p0 += __shfl_down(p0, o);
        p1 += __shfl_down(p1, o);
    }
    if (lane == 0) {
        u0[2 * n]     = p0 + b2[0];
        u0[2 * n + 1] = p1 + b2[1];
    }
}

// ---- k_agg2: second aggregation + Lorentz->Poincare pointwise (weights inline) ----

__global__ __launch_bounds__(256) void k_agg2(const float* __restrict__ u0,
                                              const int* __restrict__ csr,
                                              const int* __restrict__ count,
                                              const float* __restrict__ scale,
                                              float* __restrict__ out) {
    int n = blockIdx.x * 4 + (threadIdx.x >> 6);
    int lane = threadIdx.x & 63;
    if (n >= N_NODES) return;
    int deg = count[n];
    float degd = (float)(deg > 0 ? deg : 1);
    const int* row = csr + (size_t)n * PAD_DEG;
    float a0 = 0.f, a1 = 0.f;
    for (int j = lane; j < deg; j += 64) {
        int s = row[j];
        int cs = count[s];
        float wq = rsqrtf((float)(cs > 0 ? cs : 1) * degd);
        float2 uv = *(const float2*)(u0 + 2 * (size_t)s);
        a0 += wq * uv.x;
        a1 += wq * uv.y;
    }
    #pragma unroll
    for (int o = 32; o > 0; o >>= 1) {
        a0 += __shfl_down(a0, o);
        a1 += __shfl_down(a1, o);
    }
    if (lane == 0) {
        float un = fmaxf(sqrtf(a0 * a0 + a1 * a1), 1e-15f);
        float t = tanhf(0.5f * un) / un;   // sinh/(1+cosh)==tanh(x/2), overflow-proof
        float p0 = a0 * t, p1 = a1 * t;
        float pn = fmaxf(sqrtf(p0 * p0 + p1 * p1), 1e-12f);
        float s = fminf(fmaxf(scale[0], 0.666f), 0.999f);
        p0 = p0 / pn * s; p1 = p1 / pn * s;
        float nn = fmaxf(sqrtf(p0 * p0 + p1 * p1), 1e-15f);
        if (nn > 1.0f) { p0 = p0 / nn; p1 = p1 / nn; }   // (1-1e-15)==1.0f in fp32
        out[2 * n]     = p0;
        out[2 * n + 1] = p1;
    }
}

// ---------------- launch ----------------

extern "C" void kernel_launch(void* const* d_in, const int* in_sizes, int n_in,
                              void* d_out, int out_size, void* d_ws, size_t ws_size,
                              hipStream_t stream) {
    const float* feature = (const float*)d_in[0];
    const int*   ei      = (const int*)d_in[1];
    const float* W1      = (const float*)d_in[2];
    const float* b1      = (const float*)d_in[3];
    const float* W2      = (const float*)d_in[4];
    const float* b2      = (const float*)d_in[5];
    const float* scale   = (const float*)d_in[6];
    float* out = (float*)d_out;

    // workspace layout (byte offsets, all 16B-aligned)
    char* W = (char*)d_ws;
    int*      count = (int*)W;                    // 10240 ints
    int*      csr   = (int*)(W + 40960);          // 800000 ints
    float*    h0    = (float*)(W + 3240960);      // 10000*256 fp32
    float*    u0    = (float*)(W + 13480960);     // 20000 floats
    _Float16* Bt_hi = (_Float16*)(W + 13560960);  // 256*512 halves
    _Float16* Bt_lo = (_Float16*)(W + 13823104);  // 256*512 halves  (~14.1 MB total)

    k_pre<<<dim3(512), dim3(256), 0, stream>>>(W1, count, Bt_hi, Bt_lo);
    k_combo<<<dim3(N_TILES + BUILD_BLKS), dim3(256), 0, stream>>>(
        feature, Bt_hi, Bt_lo, b1, h0, ei, count, csr);
    k_agg1<<<dim3((N_NODES + 3) / 4), dim3(256), 0, stream>>>(h0, csr, count, W2, b2, u0);
    k_agg2<<<dim3((N_NODES + 3) / 4), dim3(256), 0, stream>>>(u0, csr, count, scale, out);
}